// Round 12
// baseline (191.085 us; speedup 1.0000x reference)
//
#include <hip/hip_runtime.h>

// RoI max pooling forward — fixed-span 4x4 clamped loads (zero runtime-trip
// inner loops). x: (1,512,50,50) f32; rois: (N,5) f32; out: (N,512,7,7) f32.
//
// R5-R9 lesson: any runtime-trip load loop compiles to load->waitcnt->fmax
// per cell (serial ~200cy L2 chains) and stalls at 55-80us. Key bound: roi
// span <= 15 cells -> bin = span/7 <= 2.143 -> EVERY bin <= 4x4 cells. So
// unroll a fixed 4x4 block with SALU-clamped indices (duplicates harmless
// under max): 16 independent float2 loads, ONE waitcnt, fmax tree. One
// latency stall per bin instead of ~5.
//
// Bounds math bit-matches XLA: roi * (1.0f/7.0f) reciprocal multiply (NOT
// true division), rintf (round-half-even), *0.0625f exact, clip to [0,H].

#define HH 50
#define WW 50
#define CC 512
#define OH 7
#define OW 7
#define NBINS 49
#define HW (HH * WW)
#define CG 128

__device__ __forceinline__ int4 compute_bounds(const float* __restrict__ r,
                                               int ph, int pw) {
    const float RCP7 = 1.0f / 7.0f;  // XLA's reciprocal for /7
    int ws = (int)rintf(r[1] * 0.0625f);
    int hs = (int)rintf(r[2] * 0.0625f);
    int we = (int)rintf(r[3] * 0.0625f);
    int he = (int)rintf(r[4] * 0.0625f);
    float roi_w = (float)max(we - ws + 1, 1);
    float roi_h = (float)max(he - hs + 1, 1);
    float bin_h = roi_h * RCP7;
    float bin_w = roi_w * RCP7;
    int hstart = min(max((int)floorf(bin_h * (float)ph) + hs, 0), HH);
    int hend   = min(max((int)ceilf (bin_h * (float)(ph + 1)) + hs, 0), HH);
    int wstart = min(max((int)floorf(bin_w * (float)pw) + ws, 0), WW);
    int wend   = min(max((int)ceilf (bin_w * (float)(pw + 1)) + ws, 0), WW);
    return make_int4(hstart, hend, wstart, wend);
}

// Kernel A: x (C, HW) -> xt (HW, C), 64x64 LDS-tiled, both sides coalesced.
__global__ __launch_bounds__(256) void transpose_x(const float* __restrict__ x,
                                                   float* __restrict__ xt) {
    __shared__ float tile[64][65];
    int tx = threadIdx.x & 63;
    int tg = threadIdx.x >> 6;  // 0..3
    int hw0 = blockIdx.x * 64;
    int c0  = blockIdx.y * 64;
    #pragma unroll
    for (int i = 0; i < 16; ++i) {
        int r  = tg * 16 + i;        // c offset in tile
        int hw = hw0 + tx;
        if (hw < HW) tile[r][tx] = x[(size_t)(c0 + r) * HW + hw];
    }
    __syncthreads();
    #pragma unroll
    for (int i = 0; i < 16; ++i) {
        int r  = tg * 16 + i;        // hw offset in tile
        int hw = hw0 + r;
        if (hw < HW) xt[(size_t)hw * CC + c0 + tx] = tile[tx][r];
    }
}

// Kernel B: block = (n, cgroup of 128 ch); wave = bin; lane = channel pair.
__global__ __launch_bounds__(256) void roi_pool_t(const float* __restrict__ xt,
                                                  const float* __restrict__ rois,
                                                  float* __restrict__ out) {
    __shared__ int4  sbnd[NBINS];
    __shared__ float stile[CG * NBINS];  // [c_local][bin] — out layout
    int tid = threadIdx.x;
    int n   = blockIdx.x >> 2;           // CC/CG = 4 cgroups
    int cg  = blockIdx.x & 3;

    const float* r = rois + (size_t)n * 5;
    if (tid < NBINS) sbnd[tid] = compute_bounds(r, tid / OW, tid % OW);
    __syncthreads();

    int lane = tid & 63;
    int wv   = tid >> 6;
    const float* base = xt + cg * CG + lane * 2;  // 8B-aligned float2 slot

    for (int bin = wv; bin < NBINS; bin += 4) {
        int4 bd = sbnd[bin];             // uniform (same addr all lanes)
        int h0 = __builtin_amdgcn_readfirstlane(bd.x);
        int h1 = __builtin_amdgcn_readfirstlane(bd.y);
        int w0 = __builtin_amdgcn_readfirstlane(bd.z);
        int w1 = __builtin_amdgcn_readfirstlane(bd.w);

        // Fixed 4x4 clamped cell block (bin span <= 4x4 guaranteed).
        // All offsets SALU; 16 independent loads -> one waitcnt.
        int hoff[4], woff[4];
        #pragma unroll
        for (int i = 0; i < 4; ++i) {
            hoff[i] = max(min(h0 + i, h1 - 1), 0) * (WW * CC);
            woff[i] = max(min(w0 + i, w1 - 1), 0) * CC;
        }
        float2 v[16];
        #pragma unroll
        for (int i = 0; i < 4; ++i)
            #pragma unroll
            for (int j = 0; j < 4; ++j)
                v[i * 4 + j] = *(const float2*)&base[hoff[i] + woff[j]];

        float m0 = v[0].x, m1 = v[0].y;
        #pragma unroll
        for (int k = 1; k < 16; ++k) {
            m0 = fmaxf(m0, v[k].x);
            m1 = fmaxf(m1, v[k].y);
        }

        bool ne = (h0 < h1) && (w0 < w1);
        // stride-49-word writes: 2 lanes/bank = free
        stile[(lane * 2 + 0) * NBINS + bin] = ne ? m0 : 0.0f;
        stile[(lane * 2 + 1) * NBINS + bin] = ne ? m1 : 0.0f;
    }
    __syncthreads();

    // 128*49 = 6272 contiguous floats = this block's exact out slice.
    size_t ob4 = (((size_t)n * CC + cg * CG) * NBINS) >> 2;
    float4* o4 = (float4*)out;
    const float4* s4 = (const float4*)stile;
    for (int t = tid; t < (CG * NBINS) / 4; t += 256)
        o4[ob4 + t] = s4[t];
}

// Fallback (ws too small for xt): R4's verified one-thread-per-output kernel.
__global__ __launch_bounds__(256) void roi_pool_fused(const float* __restrict__ x,
                                                      const float* __restrict__ rois,
                                                      float* __restrict__ out,
                                                      int total) {
    int idx = blockIdx.x * blockDim.x + threadIdx.x;
    if (idx >= total) return;
    int pw = idx % OW;
    int t  = idx / OW;
    int ph = t % OH;
    t /= OH;
    int c = t % CC;
    int n = t / CC;
    const float* r = rois + (size_t)n * 5;
    int4 bnd = compute_bounds(r, ph, pw);
    int b = (int)r[0];
    const float* plane = x + ((size_t)b * CC + c) * HW;
    float m = -INFINITY;
    for (int h = bnd.x; h < bnd.y; ++h) {
        const float* row = plane + h * WW;
        for (int w = bnd.z; w < bnd.w; ++w)
            m = fmaxf(m, row[w]);
    }
    bool nonempty = (bnd.x < bnd.y) && (bnd.z < bnd.w);
    out[idx] = nonempty ? m : 0.0f;
}

extern "C" void kernel_launch(void* const* d_in, const int* in_sizes, int n_in,
                              void* d_out, int out_size, void* d_ws, size_t ws_size,
                              hipStream_t stream) {
    const float* x    = (const float*)d_in[0];
    const float* rois = (const float*)d_in[1];
    float* out = (float*)d_out;
    int nrois = in_sizes[1] / 5;

    size_t need = (size_t)HW * CC * sizeof(float);  // 5.12 MB for xt
    if (ws_size >= need) {
        float* xt = (float*)d_ws;
        transpose_x<<<dim3((HW + 63) / 64, CC / 64), 256, 0, stream>>>(x, xt);
        roi_pool_t<<<nrois * (CC / CG), 256, 0, stream>>>(xt, rois, out);
    } else {
        roi_pool_fused<<<(out_size + 255) / 256, 256, 0, stream>>>(x, rois, out,
                                                                   out_size);
    }
}

// Round 13
// 143.068 us; speedup vs baseline: 1.3356x; 1.3356x over previous
//
#include <hip/hip_runtime.h>

// RoI max pooling forward — row-register colmax scheme.
// x: (1,512,50,50) f32; rois: (N,5) f32; out: (N,512,7,7) f32
//
// R12 lesson: fixed 4x4/bin clamped loads killed latency chains but 3.4x
// duplicated L2 traffic (1.6 GB) became the wall (VALUBusy 16%). R13 loads
// each roi cell ~once: wave owns a ph-row; loads the roi's full w-extent
// (fixed 16-wide static block, ONE waitcnt per h-row) into colmax[16] regs;
// then the 7 pw-bins reduce over colmax with compile-time-unrolled j and
// wave-uniform (scalar) masks. No dynamic reg indexing, no per-bin gathers.
// NOTE: 16 (not 15) wide because f32 ceil(bin*7) can reach roi_w+1; the
// reference genuinely reads that extra column (clamped to map edge only).
//
// Bounds math bit-matches XLA: roi * (1.0f/7.0f) reciprocal multiply (NOT
// true division), rintf (round-half-even), *0.0625f exact, clip to [0,H].

#define HH 50
#define WW 50
#define CC 512
#define OH 7
#define OW 7
#define NBINS 49
#define HW (HH * WW)
#define CG 128

__device__ __forceinline__ int2 dim_bounds(float lo_px, float hi_px, int p,
                                           int limit) {
    const float RCP7 = 1.0f / 7.0f;  // XLA's reciprocal for /7
    int s = (int)rintf(lo_px * 0.0625f);
    int e = (int)rintf(hi_px * 0.0625f);
    float span = (float)max(e - s + 1, 1);
    float bin  = span * RCP7;
    int b0 = min(max((int)floorf(bin * (float)p) + s, 0), limit);
    int b1 = min(max((int)ceilf (bin * (float)(p + 1)) + s, 0), limit);
    return make_int2(b0, b1);
}

__device__ __forceinline__ int4 compute_bounds(const float* __restrict__ r,
                                               int ph, int pw) {
    int2 hb = dim_bounds(r[2], r[4], ph, HH);
    int2 wb = dim_bounds(r[1], r[3], pw, WW);
    return make_int4(hb.x, hb.y, wb.x, wb.y);
}

// Kernel A: x (C, HW) -> xt (HW, C), 64x64 LDS-tiled, both sides coalesced.
__global__ __launch_bounds__(256) void transpose_x(const float* __restrict__ x,
                                                   float* __restrict__ xt) {
    __shared__ float tile[64][65];
    int tx = threadIdx.x & 63;
    int tg = threadIdx.x >> 6;  // 0..3
    int hw0 = blockIdx.x * 64;
    int c0  = blockIdx.y * 64;
    #pragma unroll
    for (int i = 0; i < 16; ++i) {
        int r  = tg * 16 + i;        // c offset in tile
        int hw = hw0 + tx;
        if (hw < HW) tile[r][tx] = x[(size_t)(c0 + r) * HW + hw];
    }
    __syncthreads();
    #pragma unroll
    for (int i = 0; i < 16; ++i) {
        int r  = tg * 16 + i;        // hw offset in tile
        int hw = hw0 + r;
        if (hw < HW) xt[(size_t)hw * CC + c0 + tx] = tile[tx][r];
    }
}

// Kernel B: block = (n, cgroup of 128 ch); wave = ph-row(s); lane = ch pair.
__global__ __launch_bounds__(256) void roi_pool_rows(
    const float* __restrict__ xt, const float* __restrict__ rois,
    float* __restrict__ out)
{
    __shared__ int2  shb[OH], swb[OW];
    __shared__ float stile[CG * NBINS];  // [c_local][bin] — out layout
    int tid = threadIdx.x;
    int n   = blockIdx.x >> 2;           // CC/CG = 4 cgroups
    int cg  = blockIdx.x & 3;

    const float* r = rois + (size_t)n * 5;
    if (tid < OH)                      shb[tid]     = dim_bounds(r[2], r[4], tid, HH);
    else if (tid >= 8 && tid < 8 + OW) swb[tid - 8] = dim_bounds(r[1], r[3], tid - 8, WW);
    __syncthreads();

    int lane = tid & 63;
    int wv   = tid >> 6;
    const float* base = xt + cg * CG + lane * 2;  // 8B-aligned float2 slot

    int W0 = __builtin_amdgcn_readfirstlane(swb[0].x);   // roi w-extent start

    // static per-pw upper bound for the j-unroll: ceil(15*(pw+1)/7)+1
    constexpr int jmax[OW] = {4, 6, 8, 10, 12, 14, 16};

    for (int phi = 0; phi < 2; ++phi) {
        int ph = wv + phi * 4;           // waves 0..3 -> {0,4},{1,5},{2,6},{3}
        if (ph >= OH) break;             // wave-uniform
        int2 hb = shb[ph];
        int h0 = __builtin_amdgcn_readfirstlane(hb.x);
        int h1 = __builtin_amdgcn_readfirstlane(hb.y);

        // w offsets, clamped to map edge only (wave-uniform)
        int woff[16];
        #pragma unroll
        for (int j = 0; j < 16; ++j)
            woff[j] = min(max(W0 + j, 0), WW - 1) * CC;

        // Phase 1: colmax[j] = max over h in [h0,h1) of cell (h, W0+j).
        // 16 independent loads per h-row -> one waitcnt each.
        float2 colmax[16];
        if (h0 < h1) {
            const float* rp = base + (size_t)(h0 * WW) * CC;
            #pragma unroll
            for (int j = 0; j < 16; ++j)
                colmax[j] = *(const float2*)&rp[woff[j]];
            for (int h = h0 + 1; h < h1; ++h) {    // <=3 iters, 16-wide body
                const float* rp2 = base + (size_t)(h * WW) * CC;
                float2 v[16];
                #pragma unroll
                for (int j = 0; j < 16; ++j)
                    v[j] = *(const float2*)&rp2[woff[j]];
                #pragma unroll
                for (int j = 0; j < 16; ++j) {
                    colmax[j].x = fmaxf(colmax[j].x, v[j].x);
                    colmax[j].y = fmaxf(colmax[j].y, v[j].y);
                }
            }
        } else {
            #pragma unroll
            for (int j = 0; j < 16; ++j)
                colmax[j] = make_float2(-INFINITY, -INFINITY);
        }

        // Phase 2: 7 pw-bins from colmax via wave-uniform masks.
        #pragma unroll
        for (int pw = 0; pw < OW; ++pw) {
            int2 wb = swb[pw];
            int j0 = __builtin_amdgcn_readfirstlane(wb.x) - W0;
            int j1 = __builtin_amdgcn_readfirstlane(wb.y) - W0;
            float mx = -INFINITY, my = -INFINITY;
            #pragma unroll
            for (int j = 0; j < jmax[pw]; ++j) {
                bool in = (j >= j0) && (j < j1);   // scalar condition
                mx = in ? fmaxf(mx, colmax[j].x) : mx;
                my = in ? fmaxf(my, colmax[j].y) : my;
            }
            bool ne = (h0 < h1) && (j0 < j1);
            int bin = ph * OW + pw;
            stile[(lane * 2 + 0) * NBINS + bin] = ne ? mx : 0.0f;
            stile[(lane * 2 + 1) * NBINS + bin] = ne ? my : 0.0f;
        }
    }
    __syncthreads();

    // 128*49 = 6272 contiguous floats = this block's exact out slice.
    size_t ob4 = (((size_t)n * CC + cg * CG) * NBINS) >> 2;
    float4* o4 = (float4*)out;
    const float4* s4 = (const float4*)stile;
    for (int t = tid; t < (CG * NBINS) / 4; t += 256)
        o4[ob4 + t] = s4[t];
}

// Fallback (ws too small for xt): R4's verified one-thread-per-output kernel.
__global__ __launch_bounds__(256) void roi_pool_fused(const float* __restrict__ x,
                                                      const float* __restrict__ rois,
                                                      float* __restrict__ out,
                                                      int total) {
    int idx = blockIdx.x * blockDim.x + threadIdx.x;
    if (idx >= total) return;
    int pw = idx % OW;
    int t  = idx / OW;
    int ph = t % OH;
    t /= OH;
    int c = t % CC;
    int n = t / CC;
    const float* r = rois + (size_t)n * 5;
    int4 bnd = compute_bounds(r, ph, pw);
    int b = (int)r[0];
    const float* plane = x + ((size_t)b * CC + c) * HW;
    float m = -INFINITY;
    for (int h = bnd.x; h < bnd.y; ++h) {
        const float* row = plane + h * WW;
        for (int w = bnd.z; w < bnd.w; ++w)
            m = fmaxf(m, row[w]);
    }
    bool nonempty = (bnd.x < bnd.y) && (bnd.z < bnd.w);
    out[idx] = nonempty ? m : 0.0f;
}

extern "C" void kernel_launch(void* const* d_in, const int* in_sizes, int n_in,
                              void* d_out, int out_size, void* d_ws, size_t ws_size,
                              hipStream_t stream) {
    const float* x    = (const float*)d_in[0];
    const float* rois = (const float*)d_in[1];
    float* out = (float*)d_out;
    int nrois = in_sizes[1] / 5;

    size_t need = (size_t)HW * CC * sizeof(float);  // 5.12 MB for xt
    if (ws_size >= need) {
        float* xt = (float*)d_ws;
        transpose_x<<<dim3((HW + 63) / 64, CC / 64), 256, 0, stream>>>(x, xt);
        roi_pool_rows<<<nrois * (CC / CG), 256, 0, stream>>>(xt, rois, out);
    } else {
        roi_pool_fused<<<(out_size + 255) / 256, 256, 0, stream>>>(x, rois, out,
                                                                   out_size);
    }
}

// Round 15
// 139.581 us; speedup vs baseline: 1.3690x; 1.0250x over previous
//
#include <hip/hip_runtime.h>

// RoI max pooling forward — colmax in LDS for runtime-indexed bin reduce.
// x: (1,512,50,50) f32; rois: (N,5) f32; out: (N,512,7,7) f32
//
// R13 lesson: phase-2 masked scan over colmax regs = ~560 VALU/wave (140
// j-iters x 2ch x cndmask+max) — VALU-bound at ~54us. Registers can't be
// runtime-indexed, but LDS can: spill colmax[16] to a per-wave LDS slot
// (stride-1, conflict-free), then each pw-bin reads its <=4 columns at
// scalar clamped indices min(j0+k, j1-1) (duplicates harmless under max):
// 4 ds_read + 3 fmax + 1 select per bin per channel. Phase 1 (16-wide
// batched row loads, ONE waitcnt per row, ~once-per-cell traffic) kept.
//
// Bounds math bit-matches XLA: roi * (1.0f/7.0f) reciprocal multiply (NOT
// true division), rintf (round-half-even), *0.0625f exact, clip to [0,H].

#define HH 50
#define WW 50
#define CC 512
#define OH 7
#define OW 7
#define NBINS 49
#define HW (HH * WW)
#define CG 128

__device__ __forceinline__ int2 dim_bounds(float lo_px, float hi_px, int p,
                                           int limit) {
    const float RCP7 = 1.0f / 7.0f;  // XLA's reciprocal for /7
    int s = (int)rintf(lo_px * 0.0625f);
    int e = (int)rintf(hi_px * 0.0625f);
    float span = (float)max(e - s + 1, 1);
    float bin  = span * RCP7;
    int b0 = min(max((int)floorf(bin * (float)p) + s, 0), limit);
    int b1 = min(max((int)ceilf (bin * (float)(p + 1)) + s, 0), limit);
    return make_int2(b0, b1);
}

__device__ __forceinline__ int4 compute_bounds(const float* __restrict__ r,
                                               int ph, int pw) {
    int2 hb = dim_bounds(r[2], r[4], ph, HH);
    int2 wb = dim_bounds(r[1], r[3], pw, WW);
    return make_int4(hb.x, hb.y, wb.x, wb.y);
}

// Kernel A: x (C, HW) -> xt (HW, C), 64x64 LDS-tiled, both sides coalesced.
__global__ __launch_bounds__(256) void transpose_x(const float* __restrict__ x,
                                                   float* __restrict__ xt) {
    __shared__ float tile[64][65];
    int tx = threadIdx.x & 63;
    int tg = threadIdx.x >> 6;  // 0..3
    int hw0 = blockIdx.x * 64;
    int c0  = blockIdx.y * 64;
    #pragma unroll
    for (int i = 0; i < 16; ++i) {
        int r  = tg * 16 + i;
        int hw = hw0 + tx;
        if (hw < HW) tile[r][tx] = x[(size_t)(c0 + r) * HW + hw];
    }
    __syncthreads();
    #pragma unroll
    for (int i = 0; i < 16; ++i) {
        int r  = tg * 16 + i;
        int hw = hw0 + r;
        if (hw < HW) xt[(size_t)hw * CC + c0 + tx] = tile[tx][r];
    }
}

// Kernel B: block = (n, cgroup of 128 ch); wave = ph-row(s); lane = ch pair.
__global__ __launch_bounds__(256) void roi_pool_rows(
    const float* __restrict__ xt, const float* __restrict__ rois,
    float* __restrict__ out)
{
    __shared__ int2  shb[OH], swb[OW];
    __shared__ float cmx[4][16][64];     // 16KB: per-wave colmax spill
    __shared__ float stile[CG * NBINS];  // 25KB: [c_local][bin] out staging
    int tid = threadIdx.x;
    int n   = blockIdx.x >> 2;           // CC/CG = 4 cgroups
    int cg  = blockIdx.x & 3;

    const float* r = rois + (size_t)n * 5;
    if (tid < OH)                      shb[tid]     = dim_bounds(r[2], r[4], tid, HH);
    else if (tid >= 8 && tid < 8 + OW) swb[tid - 8] = dim_bounds(r[1], r[3], tid - 8, WW);
    __syncthreads();

    int lane = tid & 63;
    int wv   = tid >> 6;
    const float* base = xt + cg * CG + lane * 2;  // 8B-aligned float2 slot

    // Hoist all w-bounds to scalars once.
    int sj0[OW], sj1[OW];
    int W0 = __builtin_amdgcn_readfirstlane(swb[0].x);
    #pragma unroll
    for (int pw = 0; pw < OW; ++pw) {
        int2 wb = swb[pw];
        sj0[pw] = __builtin_amdgcn_readfirstlane(wb.x) - W0;
        sj1[pw] = __builtin_amdgcn_readfirstlane(wb.y) - W0;
    }
    // w offsets clamped to map edge (wave-uniform scalars)
    int woff[16];
    #pragma unroll
    for (int j = 0; j < 16; ++j)
        woff[j] = min(max(W0 + j, 0), WW - 1) * CC;

    for (int phi = 0; phi < 2; ++phi) {
        int ph = wv + phi * 4;           // waves 0..3 -> {0,4},{1,5},{2,6},{3}
        if (ph >= OH) break;             // wave-uniform
        int2 hb = shb[ph];
        int h0 = __builtin_amdgcn_readfirstlane(hb.x);
        int h1 = __builtin_amdgcn_readfirstlane(hb.y);

        // Phase 1: colmax[j] over h in [h0,h1); 16 loads per row, one waitcnt.
        float2 colmax[16];
        if (h0 < h1) {
            const float* rp = base + (size_t)(h0 * WW) * CC;
            #pragma unroll
            for (int j = 0; j < 16; ++j)
                colmax[j] = *(const float2*)&rp[woff[j]];
            for (int h = h0 + 1; h < h1; ++h) {    // <=3 iters
                const float* rp2 = base + (size_t)(h * WW) * CC;
                float2 v[16];
                #pragma unroll
                for (int j = 0; j < 16; ++j)
                    v[j] = *(const float2*)&rp2[woff[j]];
                #pragma unroll
                for (int j = 0; j < 16; ++j) {
                    colmax[j].x = fmaxf(colmax[j].x, v[j].x);
                    colmax[j].y = fmaxf(colmax[j].y, v[j].y);
                }
            }
        } else {
            #pragma unroll
            for (int j = 0; j < 16; ++j)
                colmax[j] = make_float2(-INFINITY, -INFINITY);
        }

        // Phase 2, per channel: spill colmax -> per-wave LDS slot (stride-1,
        // conflict-free), then each pw reads its <=4 cols at runtime scalar
        // indices (clamped; duplicates harmless under max).
        #pragma unroll
        for (int cc = 0; cc < 2; ++cc) {
            #pragma unroll
            for (int j = 0; j < 16; ++j)
                cmx[wv][j][lane] = cc ? colmax[j].y : colmax[j].x;
            #pragma unroll
            for (int pw = 0; pw < OW; ++pw) {
                int j0 = sj0[pw], j1 = sj1[pw];
                int e  = max(j1 - 1, 0);
                int r0 = min(j0,     e), r1 = min(j0 + 1, e);
                int r2 = min(j0 + 2, e), r3 = min(j0 + 3, e);
                float a = cmx[wv][r0][lane];
                float b = cmx[wv][r1][lane];
                float c = cmx[wv][r2][lane];
                float d = cmx[wv][r3][lane];
                float m = fmaxf(fmaxf(a, b), fmaxf(c, d));
                bool ne = (h0 < h1) && (j0 < j1);
                stile[(lane * 2 + cc) * NBINS + ph * OW + pw] = ne ? m : 0.0f;
            }
        }
    }
    __syncthreads();

    // 128*49 = 6272 contiguous floats = this block's exact out slice.
    size_t ob4 = (((size_t)n * CC + cg * CG) * NBINS) >> 2;
    float4* o4 = (float4*)out;
    const float4* s4 = (const float4*)stile;
    for (int t = tid; t < (CG * NBINS) / 4; t += 256)
        o4[ob4 + t] = s4[t];
}

// Fallback (ws too small for xt): R4's verified one-thread-per-output kernel.
__global__ __launch_bounds__(256) void roi_pool_fused(const float* __restrict__ x,
                                                      const float* __restrict__ rois,
                                                      float* __restrict__ out,
                                                      int total) {
    int idx = blockIdx.x * blockDim.x + threadIdx.x;
    if (idx >= total) return;
    int pw = idx % OW;
    int t  = idx / OW;
    int ph = t % OH;
    t /= OH;
    int c = t % CC;
    int n = t / CC;
    const float* r = rois + (size_t)n * 5;
    int4 bnd = compute_bounds(r, ph, pw);
    int b = (int)r[0];
    const float* plane = x + ((size_t)b * CC + c) * HW;
    float m = -INFINITY;
    for (int h = bnd.x; h < bnd.y; ++h) {
        const float* row = plane + h * WW;
        for (int w = bnd.z; w < bnd.w; ++w)
            m = fmaxf(m, row[w]);
    }
    bool nonempty = (bnd.x < bnd.y) && (bnd.z < bnd.w);
    out[idx] = nonempty ? m : 0.0f;
}

extern "C" void kernel_launch(void* const* d_in, const int* in_sizes, int n_in,
                              void* d_out, int out_size, void* d_ws, size_t ws_size,
                              hipStream_t stream) {
    const float* x    = (const float*)d_in[0];
    const float* rois = (const float*)d_in[1];
    float* out = (float*)d_out;
    int nrois = in_sizes[1] / 5;

    size_t need = (size_t)HW * CC * sizeof(float);  // 5.12 MB for xt
    if (ws_size >= need) {
        float* xt = (float*)d_ws;
        transpose_x<<<dim3((HW + 63) / 64, CC / 64), 256, 0, stream>>>(x, xt);
        roi_pool_rows<<<nrois * (CC / CG), 256, 0, stream>>>(xt, rois, out);
    } else {
        roi_pool_fused<<<(out_size + 255) / 256, 256, 0, stream>>>(x, rois, out,
                                                                   out_size);
    }
}